// Round 2
// baseline (1228.038 us; speedup 1.0000x reference)
//
#include <hip/hip_runtime.h>

typedef __bf16 bf16_t;
typedef bf16_t bf16x8 __attribute__((ext_vector_type(8)));
typedef float floatx4 __attribute__((ext_vector_type(4)));

#define HIDDEN 2048
#define NHEADS 32
#define NKV 8
#define HD 64
#define INTER 8192
#define SEQQ 2048
#define SEQK 2048
#define NBATCH 2
#define NEGBIG (-3.0e38f)

__device__ __forceinline__ floatx4 mfma16(bf16x8 a, bf16x8 b, floatx4 c) {
  return __builtin_amdgcn_mfma_f32_16x16x32_bf16(a, b, c, 0, 0, 0);
}

// pack 8 f32 -> 8 bf16 (as uint4) from two float4 loads
__device__ __forceinline__ uint4 pack8(const float* __restrict__ p) {
  float4 f0 = *(const float4*)p;
  float4 f1 = *(const float4*)(p + 4);
  union { uint4 u; bf16_t e[8]; } r;
  r.e[0] = (bf16_t)f0.x; r.e[1] = (bf16_t)f0.y; r.e[2] = (bf16_t)f0.z; r.e[3] = (bf16_t)f0.w;
  r.e[4] = (bf16_t)f1.x; r.e[5] = (bf16_t)f1.y; r.e[6] = (bf16_t)f1.z; r.e[7] = (bf16_t)f1.w;
  return r.u;
}

// ---------------- f32 -> bf16 bulk convert ----------------
__global__ __launch_bounds__(256) void cvt_kernel(const float* __restrict__ src,
                                                  bf16_t* __restrict__ dst, int n8) {
  const int stride = gridDim.x * 256;
  for (int i = blockIdx.x * 256 + threadIdx.x; i < n8; i += stride)
    *(uint4*)(dst + (size_t)i * 8) = pack8(src + (size_t)i * 8);
}

// ---------------- RMSNorm: one row (2048 f32) per 256-thread block -> bf16 ----------------
__global__ __launch_bounds__(256) void rmsnorm_kernel(const float* __restrict__ x,
                                                      const float* __restrict__ w,
                                                      bf16_t* __restrict__ y) {
  const int row = blockIdx.x;
  const int tid = threadIdx.x;
  const float* xr = x + (size_t)row * HIDDEN + tid * 8;
  float4 x0 = *(const float4*)xr;
  float4 x1 = *(const float4*)(xr + 4);
  float xf[8] = {x0.x, x0.y, x0.z, x0.w, x1.x, x1.y, x1.z, x1.w};
  float ss = 0.f;
#pragma unroll
  for (int j = 0; j < 8; ++j) ss += xf[j] * xf[j];
#pragma unroll
  for (int off = 32; off >= 1; off >>= 1) ss += __shfl_xor(ss, off);
  __shared__ float red[4];
  if ((tid & 63) == 0) red[tid >> 6] = ss;
  __syncthreads();
  float tot = red[0] + red[1] + red[2] + red[3];
  float rs = 1.0f / sqrtf(tot / (float)HIDDEN + 1e-5f);
  const float* wr = w + tid * 8;
  float4 w0 = *(const float4*)wr;
  float4 w1 = *(const float4*)(wr + 4);
  float wf[8] = {w0.x, w0.y, w0.z, w0.w, w1.x, w1.y, w1.z, w1.w};
  bf16x8 ov;
#pragma unroll
  for (int j = 0; j < 8; ++j) ov[j] = (bf16_t)(xf[j] * rs * wf[j]);
  *(bf16x8*)(y + (size_t)row * HIDDEN + tid * 8) = ov;
}

// ---------------- staging helpers (rule #21 both-sides XOR swizzle) ------------------------
// LDS tile rows of 64 bf16 (128 B = 8 slots of 16 B). LDS slot s of row r holds global
// col-slot (s ^ (r&7)): linear LDS dest for global_load_lds, inverse swizzle on the global
// source address, same XOR on ds_read. Proven conflict-free (round-1: SQ_LDS_BANK_CONFLICT=0).

// one global_load_lds issue for a 512-thread block: 64 rows (i*64..), 8 KiB
__device__ __forceinline__ void stg512(bf16_t* lds, const bf16_t* src, int ldK, int i) {
  const int tid = (int)threadIdx.x;
  const int row = i * 64 + (tid >> 3);
  const int col = (((tid & 7) ^ (row & 7)) * 8);
  __builtin_amdgcn_global_load_lds(
      (const __attribute__((address_space(1))) void*)(src + (size_t)row * ldK + col),
      (__attribute__((address_space(3))) void*)(lds + i * 4096 + (tid >> 6) * 512), 16, 0, 0);
}

__device__ __forceinline__ bf16x8 ldfrag(const bf16_t* lds, int row, int kslot) {
  return *(const bf16x8*)(lds + row * 64 + ((kslot ^ (row & 7)) * 8));
}

// ---------------- deep-pipelined 256x128 GEMM (tri-buffer, counted vmcnt) -----------------
// C[m,n] = sum_k A[m,k] * W[n,k] (+ f32 resid). BK=64, 8 waves 4Mx2N, wave tile 64x64.
// Tile t reads buf t%3; tile t+2 staged into buf (t+2)%3 (== buf of dead tile t-1).
// Per tile: s_waitcnt vmcnt(6)+s_barrier (6 = next tile's in-flight loads; never drain 0).
template <int EPI, typename CT>  // EPI 0: C=val (CT=bf16); 1: C=val+resid (CT=float)
__global__ __launch_bounds__(512) void gemm256(const bf16_t* __restrict__ A,
                                               const bf16_t* __restrict__ W,
                                               const float* __restrict__ resid,
                                               CT* __restrict__ C, int Kd, int N) {
  __shared__ __align__(16) bf16_t AS[3][256 * 64];
  __shared__ __align__(16) bf16_t BS[3][128 * 64];
  const int tid = threadIdx.x;
  const int wid = tid >> 6, lane = tid & 63, quad = lane >> 4, l15 = lane & 15;
  const int wr = wid >> 1, wc = wid & 1;
  // column-major linearization + bijective XCD chunking (nwg % 8 == 0 for all our grids)
  const int nbx = gridDim.x, nby = gridDim.y;
  const int nwg = nbx * nby;
  const int wgid = (int)blockIdx.x * nby + (int)blockIdx.y;
  const int swz = (wgid & 7) * (nwg >> 3) + (wgid >> 3);
  const int bx = swz / nby, by = swz - bx * nby;
  const int m0 = by * 256, n0 = bx * 128;

  floatx4 acc[4][4];
  floatx4 zero = {0.f, 0.f, 0.f, 0.f};
#pragma unroll
  for (int mi = 0; mi < 4; ++mi)
#pragma unroll
    for (int ni = 0; ni < 4; ++ni) acc[mi][ni] = zero;

  const bf16_t* Ab = A + (size_t)m0 * Kd;
  const bf16_t* Wb = W + (size_t)n0 * Kd;
  const int NT = Kd >> 6;

  // prologue: stage tiles 0 and 1 (6 loads each per wave)
#pragma unroll
  for (int i = 0; i < 4; ++i) stg512(AS[0], Ab, Kd, i);
#pragma unroll
  for (int i = 0; i < 2; ++i) stg512(BS[0], Wb, Kd, i);
#pragma unroll
  for (int i = 0; i < 4; ++i) stg512(AS[1], Ab + 64, Kd, i);
#pragma unroll
  for (int i = 0; i < 2; ++i) stg512(BS[1], Wb + 64, Kd, i);

  for (int t = 0; t < NT; ++t) {
    const int b = t % 3;
    const bf16_t* As = &AS[b][0];
    const bf16_t* Bs = &BS[b][0];
    // tile t's 6 loads are the oldest; next tile's 6 may stay in flight
    if (t < NT - 1)
      asm volatile("s_waitcnt vmcnt(6)\n\ts_barrier" ::: "memory");
    else
      asm volatile("s_waitcnt vmcnt(0)\n\ts_barrier" ::: "memory");
    const int t2 = t + 2;
    const bool pf = (t2 < NT);
    bf16_t* As2 = &AS[t2 % 3][0];
    bf16_t* Bs2 = &BS[t2 % 3][0];
    const bf16_t* Ag = Ab + t2 * 64;
    const bf16_t* Bg = Wb + t2 * 64;

    // ---- phase 0 (k 0..31)
    if (pf) { stg512(As2, Ag, Kd, 0); stg512(As2, Ag, Kd, 1); stg512(Bs2, Bg, Kd, 0); }
    {
      bf16x8 af[4], bfr[4];
#pragma unroll
      for (int mi = 0; mi < 4; ++mi) af[mi] = ldfrag(As, wr * 64 + mi * 16 + l15, quad);
#pragma unroll
      for (int ni = 0; ni < 4; ++ni) bfr[ni] = ldfrag(Bs, wc * 64 + ni * 16 + l15, quad);
      __builtin_amdgcn_s_setprio(1);
#pragma unroll
      for (int mi = 0; mi < 4; ++mi)
#pragma unroll
        for (int ni = 0; ni < 4; ++ni) acc[mi][ni] = mfma16(af[mi], bfr[ni], acc[mi][ni]);
      __builtin_amdgcn_s_setprio(0);
    }
    // ---- phase 1 (k 32..63)
    if (pf) { stg512(As2, Ag, Kd, 2); stg512(As2, Ag, Kd, 3); stg512(Bs2, Bg, Kd, 1); }
    {
      bf16x8 af[4], bfr[4];
#pragma unroll
      for (int mi = 0; mi < 4; ++mi) af[mi] = ldfrag(As, wr * 64 + mi * 16 + l15, 4 + quad);
#pragma unroll
      for (int ni = 0; ni < 4; ++ni) bfr[ni] = ldfrag(Bs, wc * 64 + ni * 16 + l15, 4 + quad);
      __builtin_amdgcn_s_setprio(1);
#pragma unroll
      for (int mi = 0; mi < 4; ++mi)
#pragma unroll
        for (int ni = 0; ni < 4; ++ni) acc[mi][ni] = mfma16(af[mi], bfr[ni], acc[mi][ni]);
      __builtin_amdgcn_s_setprio(0);
    }
  }

#pragma unroll
  for (int mi = 0; mi < 4; ++mi) {
    const int mb = m0 + wr * 64 + mi * 16 + quad * 4;
#pragma unroll
    for (int ni = 0; ni < 4; ++ni) {
      const int n = n0 + wc * 64 + ni * 16 + l15;
      floatx4 v = acc[mi][ni];
#pragma unroll
      for (int r = 0; r < 4; ++r) {
        size_t idx = (size_t)(mb + r) * N + n;
        float val = v[r];
        if (EPI == 1) val += resid[idx];
        C[idx] = (CT)val;
      }
    }
  }
}

// ---------------- fused gate/up, same deep pipeline: 256x64 tile, SiLU epilogue ----------
__global__ __launch_bounds__(512) void gateup256(const bf16_t* __restrict__ A,
                                                 const bf16_t* __restrict__ Wg,
                                                 const bf16_t* __restrict__ Wu,
                                                 bf16_t* __restrict__ C, int Kd, int N) {
  __shared__ __align__(16) bf16_t AS[3][256 * 64];
  __shared__ __align__(16) bf16_t GS[3][64 * 64];
  __shared__ __align__(16) bf16_t US[3][64 * 64];
  const int tid = threadIdx.x;
  const int wid = tid >> 6, lane = tid & 63, quad = lane >> 4, l15 = lane & 15;
  const int wr = wid >> 1, wc = wid & 1;
  const int nbx = gridDim.x, nby = gridDim.y;
  const int nwg = nbx * nby;
  const int wgid = (int)blockIdx.x * nby + (int)blockIdx.y;
  const int swz = (wgid & 7) * (nwg >> 3) + (wgid >> 3);
  const int bx = swz / nby, by = swz - bx * nby;
  const int m0 = by * 256, n0 = bx * 64;

  floatx4 accg[4][2], accu[4][2];
  floatx4 zero = {0.f, 0.f, 0.f, 0.f};
#pragma unroll
  for (int mi = 0; mi < 4; ++mi)
#pragma unroll
    for (int ni = 0; ni < 2; ++ni) { accg[mi][ni] = zero; accu[mi][ni] = zero; }

  const bf16_t* Ab = A + (size_t)m0 * Kd;
  const bf16_t* Gb = Wg + (size_t)n0 * Kd;
  const bf16_t* Ub = Wu + (size_t)n0 * Kd;
  const int NT = Kd >> 6;

#pragma unroll
  for (int i = 0; i < 4; ++i) stg512(AS[0], Ab, Kd, i);
  stg512(GS[0], Gb, Kd, 0);
  stg512(US[0], Ub, Kd, 0);
#pragma unroll
  for (int i = 0; i < 4; ++i) stg512(AS[1], Ab + 64, Kd, i);
  stg512(GS[1], Gb + 64, Kd, 0);
  stg512(US[1], Ub + 64, Kd, 0);

  for (int t = 0; t < NT; ++t) {
    const int b = t % 3;
    const bf16_t* As = &AS[b][0];
    const bf16_t* Gs = &GS[b][0];
    const bf16_t* Us = &US[b][0];
    if (t < NT - 1)
      asm volatile("s_waitcnt vmcnt(6)\n\ts_barrier" ::: "memory");
    else
      asm volatile("s_waitcnt vmcnt(0)\n\ts_barrier" ::: "memory");
    const int t2 = t + 2;
    const bool pf = (t2 < NT);
    bf16_t* As2 = &AS[t2 % 3][0];
    bf16_t* Gs2 = &GS[t2 % 3][0];
    bf16_t* Us2 = &US[t2 % 3][0];
    const bf16_t* Ag = Ab + t2 * 64;
    const bf16_t* Gg = Gb + t2 * 64;
    const bf16_t* Ug = Ub + t2 * 64;

    // ---- phase 0 (k 0..31)
    if (pf) { stg512(As2, Ag, Kd, 0); stg512(As2, Ag, Kd, 1); stg512(Gs2, Gg, Kd, 0); }
    {
      bf16x8 af[4], gf[2], uf[2];
#pragma unroll
      for (int mi = 0; mi < 4; ++mi) af[mi] = ldfrag(As, wr * 64 + mi * 16 + l15, quad);
#pragma unroll
      for (int ni = 0; ni < 2; ++ni) {
        gf[ni] = ldfrag(Gs, wc * 32 + ni * 16 + l15, quad);
        uf[ni] = ldfrag(Us, wc * 32 + ni * 16 + l15, quad);
      }
      __builtin_amdgcn_s_setprio(1);
#pragma unroll
      for (int mi = 0; mi < 4; ++mi)
#pragma unroll
        for (int ni = 0; ni < 2; ++ni) {
          accg[mi][ni] = mfma16(af[mi], gf[ni], accg[mi][ni]);
          accu[mi][ni] = mfma16(af[mi], uf[ni], accu[mi][ni]);
        }
      __builtin_amdgcn_s_setprio(0);
    }
    // ---- phase 1 (k 32..63)
    if (pf) { stg512(As2, Ag, Kd, 2); stg512(As2, Ag, Kd, 3); stg512(Us2, Ug, Kd, 0); }
    {
      bf16x8 af[4], gf[2], uf[2];
#pragma unroll
      for (int mi = 0; mi < 4; ++mi) af[mi] = ldfrag(As, wr * 64 + mi * 16 + l15, 4 + quad);
#pragma unroll
      for (int ni = 0; ni < 2; ++ni) {
        gf[ni] = ldfrag(Gs, wc * 32 + ni * 16 + l15, 4 + quad);
        uf[ni] = ldfrag(Us, wc * 32 + ni * 16 + l15, 4 + quad);
      }
      __builtin_amdgcn_s_setprio(1);
#pragma unroll
      for (int mi = 0; mi < 4; ++mi)
#pragma unroll
        for (int ni = 0; ni < 2; ++ni) {
          accg[mi][ni] = mfma16(af[mi], gf[ni], accg[mi][ni]);
          accu[mi][ni] = mfma16(af[mi], uf[ni], accu[mi][ni]);
        }
      __builtin_amdgcn_s_setprio(0);
    }
  }

#pragma unroll
  for (int mi = 0; mi < 4; ++mi) {
    const int mb = m0 + wr * 64 + mi * 16 + quad * 4;
#pragma unroll
    for (int ni = 0; ni < 2; ++ni) {
      const int n = n0 + wc * 32 + ni * 16 + l15;
#pragma unroll
      for (int r = 0; r < 4; ++r) {
        float g = accg[mi][ni][r];
        float u = accu[mi][ni][r];
        float act = g / (1.f + __expf(-g)) * u;
        C[(size_t)(mb + r) * N + n] = (bf16_t)act;
      }
    }
  }
}

// ---------------- Flash attention, bf16 K/V input (segment mask + causal, GQA 4:1) --------
__global__ __launch_bounds__(256) void attn16(const bf16_t* __restrict__ qbuf,
                                              const bf16_t* __restrict__ kbuf,
                                              const bf16_t* __restrict__ vbuf,
                                              const int* __restrict__ cuq,
                                              const int* __restrict__ cuk,
                                              bf16_t* __restrict__ obuf) {
  const int qt = blockIdx.x, h = blockIdx.y, b = blockIdx.z;
  const int hk = h >> 2;
  const int tid = threadIdx.x;
  const int wid = tid >> 6, lane = tid & 63, quad = lane >> 4, l15 = lane & 15;
  __shared__ __align__(16) bf16_t Kt[64 * 72];
  __shared__ __align__(16) bf16_t Vt[64 * 72];  // transposed: Vt[d][k]
  __shared__ __align__(16) bf16_t Pt[64 * 72];
  const int cq1 = cuq[1], ck1 = cuk[1];

  const int qrow_a = qt * 64 + wid * 16 + l15;
  const bf16_t* qp = qbuf + ((size_t)(b * SEQQ + qrow_a)) * HIDDEN + h * HD;
  bf16x8 qf0 = *(const bf16x8*)(qp + quad * 8);
  bf16x8 qf1 = *(const bf16x8*)(qp + 32 + quad * 8);

  floatx4 Of[4];
  floatx4 zero = {0.f, 0.f, 0.f, 0.f};
#pragma unroll
  for (int df = 0; df < 4; ++df) Of[df] = zero;
  float m_r[4], l_r[4];
#pragma unroll
  for (int r = 0; r < 4; ++r) { m_r[r] = -1e30f; l_r[r] = 0.f; }
  const int q_row0 = qt * 64 + wid * 16 + quad * 4;
  int seg_q[4];
#pragma unroll
  for (int r = 0; r < 4; ++r) seg_q[r] = (q_row0 + r >= cq1) ? 1 : 0;
  const bool blk_seg1 = (qt * 64 >= cq1);

  const int stag_row = tid >> 3;
  const int stag_c = (tid & 7) * 8;
  const int kt_start = blk_seg1 ? (ck1 >> 6) : 0;

  for (int kt = kt_start; kt <= qt; ++kt) {
    __syncthreads();
#pragma unroll
    for (int i = 0; i < 2; ++i) {
      const int row = stag_row + i * 32;
      const size_t goff = ((size_t)((b * SEQK + kt * 64 + row) * NKV + hk)) * HD + stag_c;
      *(uint4*)&Kt[row * 72 + stag_c] = *(const uint4*)(kbuf + goff);
      bf16x8 vv = *(const bf16x8*)(vbuf + goff);
#pragma unroll
      for (int j = 0; j < 8; ++j) Vt[(stag_c + j) * 72 + row] = vv[j];
    }
    __syncthreads();

    floatx4 sf[4];
#pragma unroll
    for (int nf = 0; nf < 4; ++nf) {
      bf16x8 kf0 = *(const bf16x8*)&Kt[(nf * 16 + l15) * 72 + quad * 8];
      bf16x8 kf1 = *(const bf16x8*)&Kt[(nf * 16 + l15) * 72 + 32 + quad * 8];
      floatx4 a = zero;
      a = mfma16(qf0, kf0, a);
      a = mfma16(qf1, kf1, a);
      sf[nf] = a;
    }

    float tmax[4];
#pragma unroll
    for (int r = 0; r < 4; ++r) tmax[r] = NEGBIG;
#pragma unroll
    for (int nf = 0; nf < 4; ++nf) {
      const int kg = kt * 64 + nf * 16 + l15;
#pragma unroll
      for (int r = 0; r < 4; ++r) {
        const int qg = q_row0 + r;
        const int sk = (kg >= ck1) ? 1 : 0;
        float s = sf[nf][r] * 0.125f;
        bool ok = (kg <= qg) && (sk == seg_q[r]);
        s = ok ? s : NEGBIG;
        sf[nf][r] = s;
        tmax[r] = fmaxf(tmax[r], s);
      }
    }
#pragma unroll
    for (int r = 0; r < 4; ++r) {
#pragma unroll
      for (int off = 1; off <= 8; off <<= 1) tmax[r] = fmaxf(tmax[r], __shfl_xor(tmax[r], off));
    }
    float alpha[4], rsum[4];
#pragma unroll
    for (int r = 0; r < 4; ++r) {
      float mn = fmaxf(m_r[r], tmax[r]);
      alpha[r] = __expf(m_r[r] - mn);
      m_r[r] = mn;
      rsum[r] = 0.f;
    }
#pragma unroll
    for (int nf = 0; nf < 4; ++nf) {
#pragma unroll
      for (int r = 0; r < 4; ++r) {
        float p = __expf(sf[nf][r] - m_r[r]);
        rsum[r] += p;
        Pt[(wid * 16 + quad * 4 + r) * 72 + nf * 16 + l15] = (bf16_t)p;
      }
    }
#pragma unroll
    for (int r = 0; r < 4; ++r) {
#pragma unroll
      for (int off = 1; off <= 8; off <<= 1) rsum[r] += __shfl_xor(rsum[r], off);
      l_r[r] = alpha[r] * l_r[r] + rsum[r];
    }
#pragma unroll
    for (int df = 0; df < 4; ++df) {
#pragma unroll
      for (int r = 0; r < 4; ++r) Of[df][r] *= alpha[r];
    }
#pragma unroll
    for (int kk = 0; kk < 2; ++kk) {
      bf16x8 pf = *(const bf16x8*)&Pt[(wid * 16 + l15) * 72 + kk * 32 + quad * 8];
#pragma unroll
      for (int df = 0; df < 4; ++df) {
        bf16x8 vf = *(const bf16x8*)&Vt[(df * 16 + l15) * 72 + kk * 32 + quad * 8];
        Of[df] = mfma16(pf, vf, Of[df]);
      }
    }
  }

  float inv[4];
#pragma unroll
  for (int r = 0; r < 4; ++r) inv[r] = (l_r[r] > 0.f) ? 1.f / l_r[r] : 0.f;
#pragma unroll
  for (int df = 0; df < 4; ++df) {
#pragma unroll
    for (int r = 0; r < 4; ++r) {
      obuf[((size_t)(b * SEQQ + q_row0 + r)) * HIDDEN + h * HD + df * 16 + l15] =
          (bf16_t)(Of[df][r] * inv[r]);
    }
  }
}

// ================= LEGACY PATH (f32 weights on the fly) — fallback if ws too small ========
template <int EPI, typename CT>
__global__ __launch_bounds__(256) void gemm_bt(const bf16_t* __restrict__ A,
                                               const float* __restrict__ W,
                                               const float* __restrict__ resid,
                                               CT* __restrict__ C,
                                               int Kd, int N) {
  const int m0 = blockIdx.y * 128, n0 = blockIdx.x * 128;
  const int tid = threadIdx.x;
  const int wid = tid >> 6, lane = tid & 63, quad = lane >> 4, l15 = lane & 15;
  const int wr = wid >> 1, wc = wid & 1;
  __shared__ __align__(16) bf16_t Asm[128 * 40];
  __shared__ __align__(16) bf16_t Bsm[128 * 40];
  floatx4 acc[4][4];
  floatx4 zero = {0.f, 0.f, 0.f, 0.f};
#pragma unroll
  for (int mi = 0; mi < 4; ++mi)
#pragma unroll
    for (int ni = 0; ni < 4; ++ni) acc[mi][ni] = zero;

  const int r0 = tid >> 2;
  const int c0 = (tid & 3) * 8;

  for (int kt = 0; kt < Kd; kt += 32) {
    __syncthreads();
    uint4 a0 = *(const uint4*)(A + (size_t)(m0 + r0) * Kd + kt + c0);
    uint4 a1 = *(const uint4*)(A + (size_t)(m0 + r0 + 64) * Kd + kt + c0);
    uint4 b0 = pack8(W + (size_t)(n0 + r0) * Kd + kt + c0);
    uint4 b1 = pack8(W + (size_t)(n0 + r0 + 64) * Kd + kt + c0);
    *(uint4*)&Asm[r0 * 40 + c0] = a0;
    *(uint4*)&Asm[(r0 + 64) * 40 + c0] = a1;
    *(uint4*)&Bsm[r0 * 40 + c0] = b0;
    *(uint4*)&Bsm[(r0 + 64) * 40 + c0] = b1;
    __syncthreads();
    bf16x8 af[4], bfrag[4];
#pragma unroll
    for (int mi = 0; mi < 4; ++mi)
      af[mi] = *(const bf16x8*)&Asm[(wr * 64 + mi * 16 + l15) * 40 + quad * 8];
#pragma unroll
    for (int ni = 0; ni < 4; ++ni)
      bfrag[ni] = *(const bf16x8*)&Bsm[(wc * 64 + ni * 16 + l15) * 40 + quad * 8];
#pragma unroll
    for (int mi = 0; mi < 4; ++mi)
#pragma unroll
      for (int ni = 0; ni < 4; ++ni)
        acc[mi][ni] = mfma16(af[mi], bfrag[ni], acc[mi][ni]);
  }

#pragma unroll
  for (int mi = 0; mi < 4; ++mi) {
    const int mb = m0 + wr * 64 + mi * 16 + quad * 4;
#pragma unroll
    for (int ni = 0; ni < 4; ++ni) {
      const int n = n0 + wc * 64 + ni * 16 + l15;
      floatx4 v = acc[mi][ni];
#pragma unroll
      for (int r = 0; r < 4; ++r) {
        size_t idx = (size_t)(mb + r) * N + n;
        float val = v[r];
        if (EPI == 1) val += resid[idx];
        C[idx] = (CT)val;
      }
    }
  }
}

__global__ __launch_bounds__(256) void gemm_gateup(const bf16_t* __restrict__ A,
                                                   const float* __restrict__ Wg,
                                                   const float* __restrict__ Wu,
                                                   bf16_t* __restrict__ C,
                                                   int Kd, int N) {
  const int m0 = blockIdx.y * 128, n0 = blockIdx.x * 128;
  const int tid = threadIdx.x;
  const int wid = tid >> 6, lane = tid & 63, quad = lane >> 4, l15 = lane & 15;
  const int wr = wid >> 1, wc = wid & 1;
  __shared__ __align__(16) bf16_t Asm[128 * 40];
  __shared__ __align__(16) bf16_t Gsm[128 * 40];
  __shared__ __align__(16) bf16_t Usm[128 * 40];
  floatx4 accg[4][4], accu[4][4];
  floatx4 zero = {0.f, 0.f, 0.f, 0.f};
#pragma unroll
  for (int mi = 0; mi < 4; ++mi)
#pragma unroll
    for (int ni = 0; ni < 4; ++ni) { accg[mi][ni] = zero; accu[mi][ni] = zero; }

  const int r0 = tid >> 2;
  const int c0 = (tid & 3) * 8;

  for (int kt = 0; kt < Kd; kt += 32) {
    __syncthreads();
    uint4 a0 = *(const uint4*)(A + (size_t)(m0 + r0) * Kd + kt + c0);
    uint4 a1 = *(const uint4*)(A + (size_t)(m0 + r0 + 64) * Kd + kt + c0);
    uint4 g0 = pack8(Wg + (size_t)(n0 + r0) * Kd + kt + c0);
    uint4 g1 = pack8(Wg + (size_t)(n0 + r0 + 64) * Kd + kt + c0);
    uint4 u0 = pack8(Wu + (size_t)(n0 + r0) * Kd + kt + c0);
    uint4 u1 = pack8(Wu + (size_t)(n0 + r0 + 64) * Kd + kt + c0);
    *(uint4*)&Asm[r0 * 40 + c0] = a0;
    *(uint4*)&Asm[(r0 + 64) * 40 + c0] = a1;
    *(uint4*)&Gsm[r0 * 40 + c0] = g0;
    *(uint4*)&Gsm[(r0 + 64) * 40 + c0] = g1;
    *(uint4*)&Usm[r0 * 40 + c0] = u0;
    *(uint4*)&Usm[(r0 + 64) * 40 + c0] = u1;
    __syncthreads();
    bf16x8 af[4];
#pragma unroll
    for (int mi = 0; mi < 4; ++mi)
      af[mi] = *(const bf16x8*)&Asm[(wr * 64 + mi * 16 + l15) * 40 + quad * 8];
#pragma unroll
    for (int ni = 0; ni < 4; ++ni) {
      bf16x8 bg = *(const bf16x8*)&Gsm[(wc * 64 + ni * 16 + l15) * 40 + quad * 8];
      bf16x8 bu = *(const bf16x8*)&Usm[(wc * 64 + ni * 16 + l15) * 40 + quad * 8];
#pragma unroll
      for (int mi = 0; mi < 4; ++mi) {
        accg[mi][ni] = mfma16(af[mi], bg, accg[mi][ni]);
        accu[mi][ni] = mfma16(af[mi], bu, accu[mi][ni]);
      }
    }
  }

#pragma unroll
  for (int mi = 0; mi < 4; ++mi) {
    const int mb = m0 + wr * 64 + mi * 16 + quad * 4;
#pragma unroll
    for (int ni = 0; ni < 4; ++ni) {
      const int n = n0 + wc * 64 + ni * 16 + l15;
#pragma unroll
      for (int r = 0; r < 4; ++r) {
        float g = accg[mi][ni][r];
        float u = accu[mi][ni][r];
        float act = g / (1.f + __expf(-g)) * u;
        C[(size_t)(mb + r) * N + n] = (bf16_t)act;
      }
    }
  }
}

__global__ __launch_bounds__(256) void attn_kernel(const bf16_t* __restrict__ qbuf,
                                                   const float* __restrict__ kbuf,
                                                   const float* __restrict__ vbuf,
                                                   const int* __restrict__ cuq,
                                                   const int* __restrict__ cuk,
                                                   bf16_t* __restrict__ obuf) {
  const int qt = blockIdx.x, h = blockIdx.y, b = blockIdx.z;
  const int hk = h >> 2;
  const int tid = threadIdx.x;
  const int wid = tid >> 6, lane = tid & 63, quad = lane >> 4, l15 = lane & 15;
  __shared__ __align__(16) bf16_t Kt[64 * 72];
  __shared__ __align__(16) bf16_t Vt[64 * 72];
  __shared__ __align__(16) bf16_t Pt[64 * 72];
  const int cq1 = cuq[1], ck1 = cuk[1];

  const int qrow_a = qt * 64 + wid * 16 + l15;
  const bf16_t* qp = qbuf + ((size_t)(b * SEQQ + qrow_a)) * HIDDEN + h * HD;
  bf16x8 qf0 = *(const bf16x8*)(qp + quad * 8);
  bf16x8 qf1 = *(const bf16x8*)(qp + 32 + quad * 8);

  floatx4 Of[4];
  floatx4 zero = {0.f, 0.f, 0.f, 0.f};
#pragma unroll
  for (int df = 0; df < 4; ++df) Of[df] = zero;
  float m_r[4], l_r[4];
#pragma unroll
  for (int r = 0; r < 4; ++r) { m_r[r] = -1e30f; l_r[r] = 0.f; }
  const int q_row0 = qt * 64 + wid * 16 + quad * 4;
  int seg_q[4];
#pragma unroll
  for (int r = 0; r < 4; ++r) seg_q[r] = (q_row0 + r >= cq1) ? 1 : 0;
  const bool blk_seg1 = (qt * 64 >= cq1);

  const int stag_row = tid >> 3;
  const int stag_c = (tid & 7) * 8;
  const int kt_start = blk_seg1 ? (ck1 >> 6) : 0;

  for (int kt = kt_start; kt <= qt; ++kt) {
    __syncthreads();
#pragma unroll
    for (int i = 0; i < 2; ++i) {
      const int row = stag_row + i * 32;
      const size_t goff = ((size_t)((b * SEQK + kt * 64 + row) * NKV + hk)) * HD + stag_c;
      uint4 kv = pack8(kbuf + goff);
      *(uint4*)&Kt[row * 72 + stag_c] = kv;
      union { uint4 u; bf16_t e[8]; } vv;
      vv.u = pack8(vbuf + goff);
#pragma unroll
      for (int j = 0; j < 8; ++j) Vt[(stag_c + j) * 72 + row] = vv.e[j];
    }
    __syncthreads();

    floatx4 sf[4];
#pragma unroll
    for (int nf = 0; nf < 4; ++nf) {
      bf16x8 kf0 = *(const bf16x8*)&Kt[(nf * 16 + l15) * 72 + quad * 8];
      bf16x8 kf1 = *(const bf16x8*)&Kt[(nf * 16 + l15) * 72 + 32 + quad * 8];
      floatx4 a = zero;
      a = mfma16(qf0, kf0, a);
      a = mfma16(qf1, kf1, a);
      sf[nf] = a;
    }

    float tmax[4];
#pragma unroll
    for (int r = 0; r < 4; ++r) tmax[r] = NEGBIG;
#pragma unroll
    for (int nf = 0; nf < 4; ++nf) {
      const int kg = kt * 64 + nf * 16 + l15;
#pragma unroll
      for (int r = 0; r < 4; ++r) {
        const int qg = q_row0 + r;
        const int sk = (kg >= ck1) ? 1 : 0;
        float s = sf[nf][r] * 0.125f;
        bool ok = (kg <= qg) && (sk == seg_q[r]);
        s = ok ? s : NEGBIG;
        sf[nf][r] = s;
        tmax[r] = fmaxf(tmax[r], s);
      }
    }
#pragma unroll
    for (int r = 0; r < 4; ++r) {
#pragma unroll
      for (int off = 1; off <= 8; off <<= 1) tmax[r] = fmaxf(tmax[r], __shfl_xor(tmax[r], off));
    }
    float alpha[4], rsum[4];
#pragma unroll
    for (int r = 0; r < 4; ++r) {
      float mn = fmaxf(m_r[r], tmax[r]);
      alpha[r] = __expf(m_r[r] - mn);
      m_r[r] = mn;
      rsum[r] = 0.f;
    }
#pragma unroll
    for (int nf = 0; nf < 4; ++nf) {
#pragma unroll
      for (int r = 0; r < 4; ++r) {
        float p = __expf(sf[nf][r] - m_r[r]);
        rsum[r] += p;
        Pt[(wid * 16 + quad * 4 + r) * 72 + nf * 16 + l15] = (bf16_t)p;
      }
    }
#pragma unroll
    for (int r = 0; r < 4; ++r) {
#pragma unroll
      for (int off = 1; off <= 8; off <<= 1) rsum[r] += __shfl_xor(rsum[r], off);
      l_r[r] = alpha[r] * l_r[r] + rsum[r];
    }
#pragma unroll
    for (int df = 0; df < 4; ++df) {
#pragma unroll
      for (int r = 0; r < 4; ++r) Of[df][r] *= alpha[r];
    }
#pragma unroll
    for (int kk = 0; kk < 2; ++kk) {
      bf16x8 pf = *(const bf16x8*)&Pt[(wid * 16 + l15) * 72 + kk * 32 + quad * 8];
#pragma unroll
      for (int df = 0; df < 4; ++df) {
        bf16x8 vf = *(const bf16x8*)&Vt[(df * 16 + l15) * 72 + kk * 32 + quad * 8];
        Of[df] = mfma16(pf, vf, Of[df]);
      }
    }
  }

  float inv[4];
#pragma unroll
  for (int r = 0; r < 4; ++r) inv[r] = (l_r[r] > 0.f) ? 1.f / l_r[r] : 0.f;
#pragma unroll
  for (int df = 0; df < 4; ++df) {
#pragma unroll
    for (int r = 0; r < 4; ++r) {
      obuf[((size_t)(b * SEQQ + q_row0 + r)) * HIDDEN + h * HD + df * 16 + l15] =
          (bf16_t)(Of[df][r] * inv[r]);
    }
  }
}

static inline int cvt_grid(int n8) {
  int g = (n8 + 255) / 256;
  return g > 2048 ? 2048 : g;
}

extern "C" void kernel_launch(void* const* d_in, const int* in_sizes, int n_in,
                              void* d_out, int out_size, void* d_ws, size_t ws_size,
                              hipStream_t stream) {
  const float* x    = (const float*)d_in[0];   // hidden_states [2,2048,2048] f32
  const float* kst  = (const float*)d_in[1];   // key_states   [2,2048,8,64] f32
  const float* vst  = (const float*)d_in[2];   // value_states [2,2048,8,64] f32
  const float* wln1 = (const float*)d_in[4];
  const float* wln2 = (const float*)d_in[5];
  const float* wq   = (const float*)d_in[6];   // [2048,2048] f32
  const float* wo   = (const float*)d_in[7];   // [2048,2048] f32
  const float* wg   = (const float*)d_in[8];   // [8192,2048] f32
  const float* wu   = (const float*)d_in[9];   // [8192,2048] f32
  const float* wd   = (const float*)d_in[10];  // [2048,8192] f32
  const int* cuq    = (const int*)d_in[11];
  const int* cuk    = (const int*)d_in[12];
  float* out = (float*)d_out;                  // f32; also holds `hidden`

  const size_t MB = 1024ull * 1024ull;
  char* ws = (char*)d_ws;
  const bool full = ws_size >= 200 * MB;
  const bool conv = ws_size >= 168 * MB;

  if (conv) {
    bf16_t* bufA = (bf16_t*)ws;                         // 16 MiB
    bf16_t* bufB = (bf16_t*)(ws + 16 * MB);             // 64 (full) / 32 MiB
    char* p = ws + 16 * MB + (full ? 64 : 32) * MB;
    bf16_t* wq16 = (bf16_t*)p; p += 8 * MB;
    bf16_t* wo16 = (bf16_t*)p; p += 8 * MB;
    bf16_t* wg16 = (bf16_t*)p; p += 32 * MB;
    bf16_t* wu16 = (bf16_t*)p; p += 32 * MB;
    bf16_t* wd16 = (bf16_t*)p; p += 32 * MB;
    bf16_t* k16  = (bf16_t*)p; p += 4 * MB;
    bf16_t* v16  = (bf16_t*)p;

    const int n8_qo = 2048 * 2048 / 8;
    const int n8_gud = 8192 * 2048 / 8;
    const int n8_kv = NBATCH * SEQK * NKV * HD / 8;
    cvt_kernel<<<cvt_grid(n8_qo), 256, 0, stream>>>(wq, wq16, n8_qo);
    cvt_kernel<<<cvt_grid(n8_qo), 256, 0, stream>>>(wo, wo16, n8_qo);
    cvt_kernel<<<cvt_grid(n8_gud), 256, 0, stream>>>(wg, wg16, n8_gud);
    cvt_kernel<<<cvt_grid(n8_gud), 256, 0, stream>>>(wu, wu16, n8_gud);
    cvt_kernel<<<cvt_grid(n8_gud), 256, 0, stream>>>(wd, wd16, n8_gud);
    cvt_kernel<<<cvt_grid(n8_kv), 256, 0, stream>>>(kst, k16, n8_kv);
    cvt_kernel<<<cvt_grid(n8_kv), 256, 0, stream>>>(vst, v16, n8_kv);

    // 1. normed = rmsnorm(x, ln1) -> bf16
    rmsnorm_kernel<<<4096, 256, 0, stream>>>(x, wln1, bufA);
    // 2. q = normed @ wq^T -> bf16   (M=4096,N=2048,K=2048)
    gemm256<0, bf16_t><<<dim3(16, 16), 512, 0, stream>>>(bufA, wq16, nullptr, bufB, 2048, 2048);
    // 3. attn -> bf16
    attn16<<<dim3(32, 32, 2), 256, 0, stream>>>(bufB, k16, v16, cuq, cuk, bufA);
    // 4. hidden = x + attn @ wo^T (f32, in d_out)
    gemm256<1, float><<<dim3(16, 16), 512, 0, stream>>>(bufA, wo16, x, out, 2048, 2048);
    // 5. normed2 = rmsnorm(hidden, ln2) -> bf16
    rmsnorm_kernel<<<4096, 256, 0, stream>>>(out, wln2, bufA);
    // 6/7. MLP
    const int nch = full ? 1 : 2;
    const int mch = 4096 / nch;
    for (int c = 0; c < nch; ++c) {
      const size_t off = (size_t)c * mch;
      gateup256<<<dim3(128, mch / 256), 512, 0, stream>>>(bufA + off * HIDDEN, wg16, wu16,
                                                          bufB, 2048, 8192);
      gemm256<1, float><<<dim3(16, mch / 256), 512, 0, stream>>>(bufB, wd16, out + off * HIDDEN,
                                                                 out + off * HIDDEN, 8192, 2048);
    }
  } else {
    // Legacy path (48 MiB workspace): on-the-fly f32->bf16 in each GEMM.
    bf16_t* bufA = (bf16_t*)ws;
    bf16_t* bufB = (bf16_t*)(ws + 16 * MB);
    rmsnorm_kernel<<<4096, 256, 0, stream>>>(x, wln1, bufA);
    gemm_bt<0, bf16_t><<<dim3(16, 32), 256, 0, stream>>>(bufA, wq, nullptr, bufB, 2048, 2048);
    attn_kernel<<<dim3(32, 32, 2), 256, 0, stream>>>(bufB, kst, vst, cuq, cuk, bufA);
    gemm_bt<1, float><<<dim3(16, 32), 256, 0, stream>>>(bufA, wo, x, out, 2048, 2048);
    rmsnorm_kernel<<<4096, 256, 0, stream>>>(out, wln2, bufA);
    for (int c = 0; c < 2; ++c) {
      const size_t off = (size_t)c * 2048;
      gemm_gateup<<<dim3(64, 16), 256, 0, stream>>>(bufA + off * HIDDEN, wg, wu, bufB, 2048, 8192);
      gemm_bt<1, float><<<dim3(16, 16), 256, 0, stream>>>(bufB, wd, out + off * HIDDEN,
                                                          out + off * HIDDEN, 8192, 2048);
    }
  }
}

// Round 3
// 1012.399 us; speedup vs baseline: 1.2130x; 1.2130x over previous
//
#include <hip/hip_runtime.h>

typedef __bf16 bf16_t;
typedef bf16_t bf16x8 __attribute__((ext_vector_type(8)));
typedef float floatx4 __attribute__((ext_vector_type(4)));

#define HIDDEN 2048
#define NHEADS 32
#define NKV 8
#define HD 64
#define INTER 8192
#define SEQQ 2048
#define SEQK 2048
#define NBATCH 2
#define NEGBIG (-3.0e38f)

__device__ __forceinline__ floatx4 mfma16(bf16x8 a, bf16x8 b, floatx4 c) {
  return __builtin_amdgcn_mfma_f32_16x16x32_bf16(a, b, c, 0, 0, 0);
}

// pack 8 f32 -> 8 bf16 (as uint4) from two float4 loads
__device__ __forceinline__ uint4 pack8(const float* __restrict__ p) {
  float4 f0 = *(const float4*)p;
  float4 f1 = *(const float4*)(p + 4);
  union { uint4 u; bf16_t e[8]; } r;
  r.e[0] = (bf16_t)f0.x; r.e[1] = (bf16_t)f0.y; r.e[2] = (bf16_t)f0.z; r.e[3] = (bf16_t)f0.w;
  r.e[4] = (bf16_t)f1.x; r.e[5] = (bf16_t)f1.y; r.e[6] = (bf16_t)f1.z; r.e[7] = (bf16_t)f1.w;
  return r.u;
}

// ---------------- f32 -> bf16 bulk convert ----------------
__global__ __launch_bounds__(256) void cvt_kernel(const float* __restrict__ src,
                                                  bf16_t* __restrict__ dst, int n8) {
  const int stride = gridDim.x * 256;
  for (int i = blockIdx.x * 256 + threadIdx.x; i < n8; i += stride)
    *(uint4*)(dst + (size_t)i * 8) = pack8(src + (size_t)i * 8);
}

// ---------------- RMSNorm: one row (2048 f32) per 256-thread block -> bf16 ----------------
__global__ __launch_bounds__(256) void rmsnorm_kernel(const float* __restrict__ x,
                                                      const float* __restrict__ w,
                                                      bf16_t* __restrict__ y) {
  const int row = blockIdx.x;
  const int tid = threadIdx.x;
  const float* xr = x + (size_t)row * HIDDEN + tid * 8;
  float4 x0 = *(const float4*)xr;
  float4 x1 = *(const float4*)(xr + 4);
  float xf[8] = {x0.x, x0.y, x0.z, x0.w, x1.x, x1.y, x1.z, x1.w};
  float ss = 0.f;
#pragma unroll
  for (int j = 0; j < 8; ++j) ss += xf[j] * xf[j];
#pragma unroll
  for (int off = 32; off >= 1; off >>= 1) ss += __shfl_xor(ss, off);
  __shared__ float red[4];
  if ((tid & 63) == 0) red[tid >> 6] = ss;
  __syncthreads();
  float tot = red[0] + red[1] + red[2] + red[3];
  float rs = 1.0f / sqrtf(tot / (float)HIDDEN + 1e-5f);
  const float* wr = w + tid * 8;
  float4 w0 = *(const float4*)wr;
  float4 w1 = *(const float4*)(wr + 4);
  float wf[8] = {w0.x, w0.y, w0.z, w0.w, w1.x, w1.y, w1.z, w1.w};
  bf16x8 ov;
#pragma unroll
  for (int j = 0; j < 8; ++j) ov[j] = (bf16_t)(xf[j] * rs * wf[j]);
  *(bf16x8*)(y + (size_t)row * HIDDEN + tid * 8) = ov;
}

// ---------------- staging helpers (rule #21 both-sides XOR swizzle) ------------------------
// LDS tile: [ROWS][64] bf16, row = 128 B = 8 slots of 16 B. LDS slot s of row r holds global
// col-slot (s ^ (r&7)); linear LDS dest for global_load_lds, inverse swizzle on global source,
// same XOR on ds_read. Verified conflict-free (SQ_LDS_BANK_CONFLICT = 0).
template <int ROWS>
__device__ __forceinline__ void stage_tile(bf16_t* lds, const bf16_t* src, int ldK) {
  const int tid = (int)threadIdx.x;
  const int wid = tid >> 6;
  const int row0 = tid >> 3;                          // 0..31 within 32-row chunk
  const int scol = (((tid & 7) ^ (row0 & 7)) * 8);    // swizzled col (elements)
#pragma unroll
  for (int i = 0; i < ROWS / 32; ++i) {
    const bf16_t* g = src + (size_t)(i * 32 + row0) * ldK + scol;
    __builtin_amdgcn_global_load_lds(
        (const __attribute__((address_space(1))) void*)g,
        (__attribute__((address_space(3))) void*)(lds + i * 2048 + wid * 512), 16, 0, 0);
  }
}

__device__ __forceinline__ bf16x8 ldfrag(const bf16_t* lds, int row, int kslot) {
  return *(const bf16x8*)(lds + row * 64 + ((kslot ^ (row & 7)) * 8));
}

// ---------------- bf16 GEMM: C[m,n] = sum_k A[m,k] * W[n,k] (+ f32 residual) --------------
// 128x128 tile, BK=64, 4 waves 2x2, each wave 64x64 (4x4 frags of 16x16x32). [round-1 verified]
template <int EPI, typename CT>  // EPI 0: C=val; 1: C=val+resid
__global__ __launch_bounds__(256) void gemm_bt16(const bf16_t* __restrict__ A,
                                                 const bf16_t* __restrict__ W,
                                                 const float* __restrict__ resid,
                                                 CT* __restrict__ C, int Kd, int N) {
  const int m0 = blockIdx.y * 128, n0 = blockIdx.x * 128;
  const int tid = threadIdx.x;
  const int wid = tid >> 6, lane = tid & 63, quad = lane >> 4, l15 = lane & 15;
  const int wr = wid >> 1, wc = wid & 1;
  __shared__ __align__(16) bf16_t Asm[128 * 64];
  __shared__ __align__(16) bf16_t Bsm[128 * 64];
  floatx4 acc[4][4];
  floatx4 zero = {0.f, 0.f, 0.f, 0.f};
#pragma unroll
  for (int mi = 0; mi < 4; ++mi)
#pragma unroll
    for (int ni = 0; ni < 4; ++ni) acc[mi][ni] = zero;

  const bf16_t* Ab = A + (size_t)m0 * Kd;
  const bf16_t* Wb = W + (size_t)n0 * Kd;

  for (int kt = 0; kt < Kd; kt += 64) {
    __syncthreads();
    stage_tile<128>(Asm, Ab + kt, Kd);
    stage_tile<128>(Bsm, Wb + kt, Kd);
    __syncthreads();
#pragma unroll
    for (int kk = 0; kk < 2; ++kk) {
      const int ks = kk * 4 + quad;
      bf16x8 af[4], bfr[4];
#pragma unroll
      for (int mi = 0; mi < 4; ++mi) af[mi] = ldfrag(Asm, wr * 64 + mi * 16 + l15, ks);
#pragma unroll
      for (int ni = 0; ni < 4; ++ni) bfr[ni] = ldfrag(Bsm, wc * 64 + ni * 16 + l15, ks);
#pragma unroll
      for (int mi = 0; mi < 4; ++mi)
#pragma unroll
        for (int ni = 0; ni < 4; ++ni) acc[mi][ni] = mfma16(af[mi], bfr[ni], acc[mi][ni]);
    }
  }

#pragma unroll
  for (int mi = 0; mi < 4; ++mi) {
    const int mb = m0 + wr * 64 + mi * 16 + quad * 4;
#pragma unroll
    for (int ni = 0; ni < 4; ++ni) {
      const int n = n0 + wc * 64 + ni * 16 + l15;
      floatx4 v = acc[mi][ni];
#pragma unroll
      for (int r = 0; r < 4; ++r) {
        size_t idx = (size_t)(mb + r) * N + n;
        float val = v[r];
        if (EPI == 1) val += resid[idx];
        C[idx] = (CT)val;
      }
    }
  }
}

// ---------------- Fused gate/up bf16 GEMM with SiLU epilogue -> bf16 [round-1 verified] ----
__global__ __launch_bounds__(256) void gateup16(const bf16_t* __restrict__ A,
                                                const bf16_t* __restrict__ Wg,
                                                const bf16_t* __restrict__ Wu,
                                                bf16_t* __restrict__ C, int Kd, int N) {
  const int m0 = blockIdx.y * 128, n0 = blockIdx.x * 64;
  const int tid = threadIdx.x;
  const int wid = tid >> 6, lane = tid & 63, quad = lane >> 4, l15 = lane & 15;
  const int wr = wid >> 1, wc = wid & 1;
  __shared__ __align__(16) bf16_t Asm[128 * 64];
  __shared__ __align__(16) bf16_t Gsm[64 * 64];
  __shared__ __align__(16) bf16_t Usm[64 * 64];
  floatx4 accg[4][2], accu[4][2];
  floatx4 zero = {0.f, 0.f, 0.f, 0.f};
#pragma unroll
  for (int mi = 0; mi < 4; ++mi)
#pragma unroll
    for (int ni = 0; ni < 2; ++ni) { accg[mi][ni] = zero; accu[mi][ni] = zero; }

  const bf16_t* Ab = A + (size_t)m0 * Kd;
  const bf16_t* Gb = Wg + (size_t)n0 * Kd;
  const bf16_t* Ub = Wu + (size_t)n0 * Kd;

  for (int kt = 0; kt < Kd; kt += 64) {
    __syncthreads();
    stage_tile<128>(Asm, Ab + kt, Kd);
    stage_tile<64>(Gsm, Gb + kt, Kd);
    stage_tile<64>(Usm, Ub + kt, Kd);
    __syncthreads();
#pragma unroll
    for (int kk = 0; kk < 2; ++kk) {
      const int ks = kk * 4 + quad;
      bf16x8 af[4];
#pragma unroll
      for (int mi = 0; mi < 4; ++mi) af[mi] = ldfrag(Asm, wr * 64 + mi * 16 + l15, ks);
#pragma unroll
      for (int ni = 0; ni < 2; ++ni) {
        bf16x8 bg = ldfrag(Gsm, wc * 32 + ni * 16 + l15, ks);
        bf16x8 bu = ldfrag(Usm, wc * 32 + ni * 16 + l15, ks);
#pragma unroll
        for (int mi = 0; mi < 4; ++mi) {
          accg[mi][ni] = mfma16(af[mi], bg, accg[mi][ni]);
          accu[mi][ni] = mfma16(af[mi], bu, accu[mi][ni]);
        }
      }
    }
  }

#pragma unroll
  for (int mi = 0; mi < 4; ++mi) {
    const int mb = m0 + wr * 64 + mi * 16 + quad * 4;
#pragma unroll
    for (int ni = 0; ni < 2; ++ni) {
      const int n = n0 + wc * 32 + ni * 16 + l15;
#pragma unroll
      for (int r = 0; r < 4; ++r) {
        float g = accg[mi][ni][r];
        float u = accu[mi][ni][r];
        float act = g / (1.f + __expf(-g)) * u;
        C[(size_t)(mb + r) * N + n] = (bf16_t)act;
      }
    }
  }
}

// ---------------- Flash attention, GQA-shared staging (segment mask + causal) -------------
// grid: (qt=32, hg=16, b=2); block 256 = 4 waves. Wave = {head h = hg*2 + (wid>>1)} x
// {q-half (wid&1)*32 rows}, 2 m-frags of 16 rows. K fragments load DIRECT from global
// (8 KB tile, L1/L2-resident, coalesced 16B/lane, broadcast across the 4 waves).
// V double-buffered in LDS with T14 split: global->regs issued BEFORE QK^T, LDS scatter
// AFTER the single per-tile barrier. One barrier per k-tile.
// Hazards: reads of Vt[p] (tile t, staged iter t-1 pre-barrier writes) are after iter-t
// barrier; writes to Vt[p^1] (tile t+1) happen after iter-t barrier, and its previous
// readers (tile t-1, iter t-1 PV) finished before that same barrier. P is per-wave LDS.
__global__ __launch_bounds__(256) void attn_gqa(const bf16_t* __restrict__ qbuf,
                                                const bf16_t* __restrict__ kbuf,
                                                const bf16_t* __restrict__ vbuf,
                                                const int* __restrict__ cuq,
                                                const int* __restrict__ cuk,
                                                bf16_t* __restrict__ obuf) {
  const int qt = blockIdx.x, hg = blockIdx.y, b = blockIdx.z;
  const int hk = hg >> 1;
  const int tid = threadIdx.x;
  const int wid = tid >> 6, lane = tid & 63, quad = lane >> 4, l15 = lane & 15;
  const int h = hg * 2 + (wid >> 1);
  const int qh = wid & 1;
  __shared__ __align__(16) bf16_t Vt[2][64 * 72];   // V^T: [d][k], double-buffered
  __shared__ __align__(16) bf16_t Pt[4 * 32 * 72];  // per-wave 32-row P scratch
  const int cq1 = cuq[1], ck1 = cuk[1];

  // Q fragments: qf[mi][ks]
  bf16x8 qf[2][2];
#pragma unroll
  for (int mi = 0; mi < 2; ++mi) {
    const int qr = qt * 64 + qh * 32 + mi * 16 + l15;
    const bf16_t* qp = qbuf + ((size_t)(b * SEQQ + qr)) * HIDDEN + h * HD;
    qf[mi][0] = *(const bf16x8*)(qp + quad * 8);
    qf[mi][1] = *(const bf16x8*)(qp + 32 + quad * 8);
  }

  floatx4 Of[2][4];
  floatx4 zero = {0.f, 0.f, 0.f, 0.f};
#pragma unroll
  for (int mi = 0; mi < 2; ++mi)
#pragma unroll
    for (int df = 0; df < 4; ++df) Of[mi][df] = zero;
  float m_r[2][4], l_r[2][4];
#pragma unroll
  for (int mi = 0; mi < 2; ++mi)
#pragma unroll
    for (int r = 0; r < 4; ++r) { m_r[mi][r] = -1e30f; l_r[mi][r] = 0.f; }

  const bool blk_seg1 = (qt * 64 >= cq1);
  const int kt_start = blk_seg1 ? (ck1 >> 6) : 0;

  const int vrow = tid >> 3;        // 0..31
  const int vc = (tid & 7) * 8;     // 0..56

  // prologue: stage V[kt_start] into buf (kt_start&1); no prior readers -> no barrier first
#pragma unroll
  for (int i = 0; i < 2; ++i) {
    const int row = vrow + i * 32;
    const size_t goff = ((size_t)((b * SEQK + kt_start * 64 + row) * NKV + hk)) * HD + vc;
    bf16x8 vv = *(const bf16x8*)(vbuf + goff);
#pragma unroll
    for (int j = 0; j < 8; ++j) Vt[kt_start & 1][(vc + j) * 72 + row] = vv[j];
  }

  for (int kt = kt_start; kt <= qt; ++kt) {
    const int p = kt & 1;
    const bool hn = (kt < qt);
    // (a) issue next V tile global->regs early (latency hides under QK^T)
    bf16x8 vvn[2];
    if (hn) {
#pragma unroll
      for (int i = 0; i < 2; ++i) {
        const int row = vrow + i * 32;
        const size_t goff = ((size_t)((b * SEQK + (kt + 1) * 64 + row) * NKV + hk)) * HD + vc;
        vvn[i] = *(const bf16x8*)(vbuf + goff);
      }
    }
    // (b) K fragments direct from global, then S = Q K^T
    bf16x8 kf[4][2];
#pragma unroll
    for (int nf = 0; nf < 4; ++nf) {
      const int krow = kt * 64 + nf * 16 + l15;
      const bf16_t* kp = kbuf + ((size_t)((b * SEQK + krow) * NKV + hk)) * HD;
      kf[nf][0] = *(const bf16x8*)(kp + quad * 8);
      kf[nf][1] = *(const bf16x8*)(kp + 32 + quad * 8);
    }
    floatx4 sf[2][4];
#pragma unroll
    for (int mi = 0; mi < 2; ++mi)
#pragma unroll
      for (int nf = 0; nf < 4; ++nf) {
        floatx4 a = zero;
        a = mfma16(qf[mi][0], kf[nf][0], a);
        a = mfma16(qf[mi][1], kf[nf][1], a);
        sf[mi][nf] = a;
      }

    // mask + row max
    float tmax[2][4];
#pragma unroll
    for (int mi = 0; mi < 2; ++mi) {
      const int q0 = qt * 64 + qh * 32 + mi * 16 + quad * 4;
#pragma unroll
      for (int r = 0; r < 4; ++r) tmax[mi][r] = NEGBIG;
#pragma unroll
      for (int nf = 0; nf < 4; ++nf) {
        const int kg = kt * 64 + nf * 16 + l15;
        const int sk = (kg >= ck1) ? 1 : 0;
#pragma unroll
        for (int r = 0; r < 4; ++r) {
          const int qg = q0 + r;
          const int sq = (qg >= cq1) ? 1 : 0;
          float s = sf[mi][nf][r] * 0.125f;
          bool ok = (kg <= qg) && (sk == sq);
          s = ok ? s : NEGBIG;
          sf[mi][nf][r] = s;
          tmax[mi][r] = fmaxf(tmax[mi][r], s);
        }
      }
#pragma unroll
      for (int r = 0; r < 4; ++r) {
#pragma unroll
        for (int off = 1; off <= 8; off <<= 1)
          tmax[mi][r] = fmaxf(tmax[mi][r], __shfl_xor(tmax[mi][r], off));
      }
    }
    float alpha[2][4], rsum[2][4];
#pragma unroll
    for (int mi = 0; mi < 2; ++mi)
#pragma unroll
      for (int r = 0; r < 4; ++r) {
        float mn = fmaxf(m_r[mi][r], tmax[mi][r]);
        alpha[mi][r] = __expf(m_r[mi][r] - mn);
        m_r[mi][r] = mn;
        rsum[mi][r] = 0.f;
      }
    // P = exp(S - m) -> per-wave LDS (C-layout)
#pragma unroll
    for (int mi = 0; mi < 2; ++mi)
#pragma unroll
      for (int nf = 0; nf < 4; ++nf)
#pragma unroll
        for (int r = 0; r < 4; ++r) {
          float pv = __expf(sf[mi][nf][r] - m_r[mi][r]);
          rsum[mi][r] += pv;
          Pt[(wid * 32 + mi * 16 + quad * 4 + r) * 72 + nf * 16 + l15] = (bf16_t)pv;
        }
#pragma unroll
    for (int mi = 0; mi < 2; ++mi)
#pragma unroll
      for (int r = 0; r < 4; ++r) {
#pragma unroll
        for (int off = 1; off <= 8; off <<= 1) rsum[mi][r] += __shfl_xor(rsum[mi][r], off);
        l_r[mi][r] = alpha[mi][r] * l_r[mi][r] + rsum[mi][r];
      }
    // rescale O
#pragma unroll
    for (int mi = 0; mi < 2; ++mi)
#pragma unroll
      for (int df = 0; df < 4; ++df)
#pragma unroll
        for (int r = 0; r < 4; ++r) Of[mi][df][r] *= alpha[mi][r];

    // (c) single per-tile barrier
    __syncthreads();

    // (d) write next V tile into the other buffer
    if (hn) {
#pragma unroll
      for (int i = 0; i < 2; ++i) {
        const int row = vrow + i * 32;
#pragma unroll
        for (int j = 0; j < 8; ++j) Vt[p ^ 1][(vc + j) * 72 + row] = vvn[i][j];
      }
    }

    // (e) PV from current buffer
#pragma unroll
    for (int kk = 0; kk < 2; ++kk) {
#pragma unroll
      for (int mi = 0; mi < 2; ++mi) {
        bf16x8 pfr = *(const bf16x8*)&Pt[(wid * 32 + mi * 16 + l15) * 72 + kk * 32 + quad * 8];
#pragma unroll
        for (int df = 0; df < 4; ++df) {
          bf16x8 vfr = *(const bf16x8*)&Vt[p][(df * 16 + l15) * 72 + kk * 32 + quad * 8];
          Of[mi][df] = mfma16(pfr, vfr, Of[mi][df]);
        }
      }
    }
  }

  // epilogue
#pragma unroll
  for (int mi = 0; mi < 2; ++mi) {
    const int q0 = qt * 64 + qh * 32 + mi * 16 + quad * 4;
#pragma unroll
    for (int r = 0; r < 4; ++r) {
      float inv = (l_r[mi][r] > 0.f) ? 1.f / l_r[mi][r] : 0.f;
#pragma unroll
      for (int df = 0; df < 4; ++df) {
        obuf[((size_t)(b * SEQQ + q0 + r)) * HIDDEN + h * HD + df * 16 + l15] =
            (bf16_t)(Of[mi][df][r] * inv);
      }
    }
  }
}

// ================= LEGACY PATH (f32 weights on the fly) — fallback if ws too small ========
template <int EPI, typename CT>
__global__ __launch_bounds__(256) void gemm_bt(const bf16_t* __restrict__ A,
                                               const float* __restrict__ W,
                                               const float* __restrict__ resid,
                                               CT* __restrict__ C,
                                               int Kd, int N) {
  const int m0 = blockIdx.y * 128, n0 = blockIdx.x * 128;
  const int tid = threadIdx.x;
  const int wid = tid >> 6, lane = tid & 63, quad = lane >> 4, l15 = lane & 15;
  const int wr = wid >> 1, wc = wid & 1;
  __shared__ __align__(16) bf16_t Asm[128 * 40];
  __shared__ __align__(16) bf16_t Bsm[128 * 40];
  floatx4 acc[4][4];
  floatx4 zero = {0.f, 0.f, 0.f, 0.f};
#pragma unroll
  for (int mi = 0; mi < 4; ++mi)
#pragma unroll
    for (int ni = 0; ni < 4; ++ni) acc[mi][ni] = zero;

  const int r0 = tid >> 2;
  const int c0 = (tid & 3) * 8;

  for (int kt = 0; kt < Kd; kt += 32) {
    __syncthreads();
    uint4 a0 = *(const uint4*)(A + (size_t)(m0 + r0) * Kd + kt + c0);
    uint4 a1 = *(const uint4*)(A + (size_t)(m0 + r0 + 64) * Kd + kt + c0);
    uint4 b0 = pack8(W + (size_t)(n0 + r0) * Kd + kt + c0);
    uint4 b1 = pack8(W + (size_t)(n0 + r0 + 64) * Kd + kt + c0);
    *(uint4*)&Asm[r0 * 40 + c0] = a0;
    *(uint4*)&Asm[(r0 + 64) * 40 + c0] = a1;
    *(uint4*)&Bsm[r0 * 40 + c0] = b0;
    *(uint4*)&Bsm[(r0 + 64) * 40 + c0] = b1;
    __syncthreads();
    bf16x8 af[4], bfrag[4];
#pragma unroll
    for (int mi = 0; mi < 4; ++mi)
      af[mi] = *(const bf16x8*)&Asm[(wr * 64 + mi * 16 + l15) * 40 + quad * 8];
#pragma unroll
    for (int ni = 0; ni < 4; ++ni)
      bfrag[ni] = *(const bf16x8*)&Bsm[(wc * 64 + ni * 16 + l15) * 40 + quad * 8];
#pragma unroll
    for (int mi = 0; mi < 4; ++mi)
#pragma unroll
      for (int ni = 0; ni < 4; ++ni)
        acc[mi][ni] = mfma16(af[mi], bfrag[ni], acc[mi][ni]);
  }

#pragma unroll
  for (int mi = 0; mi < 4; ++mi) {
    const int mb = m0 + wr * 64 + mi * 16 + quad * 4;
#pragma unroll
    for (int ni = 0; ni < 4; ++ni) {
      const int n = n0 + wc * 64 + ni * 16 + l15;
      floatx4 v = acc[mi][ni];
#pragma unroll
      for (int r = 0; r < 4; ++r) {
        size_t idx = (size_t)(mb + r) * N + n;
        float val = v[r];
        if (EPI == 1) val += resid[idx];
        C[idx] = (CT)val;
      }
    }
  }
}

__global__ __launch_bounds__(256) void gemm_gateup(const bf16_t* __restrict__ A,
                                                   const float* __restrict__ Wg,
                                                   const float* __restrict__ Wu,
                                                   bf16_t* __restrict__ C,
                                                   int Kd, int N) {
  const int m0 = blockIdx.y * 128, n0 = blockIdx.x * 128;
  const int tid = threadIdx.x;
  const int wid = tid >> 6, lane = tid & 63, quad = lane >> 4, l15 = lane & 15;
  const int wr = wid >> 1, wc = wid & 1;
  __shared__ __align__(16) bf16_t Asm[128 * 40];
  __shared__ __align__(16) bf16_t Gsm[128 * 40];
  __shared__ __align__(16) bf16_t Usm[128 * 40];
  floatx4 accg[4][4], accu[4][4];
  floatx4 zero = {0.f, 0.f, 0.f, 0.f};
#pragma unroll
  for (int mi = 0; mi < 4; ++mi)
#pragma unroll
    for (int ni = 0; ni < 4; ++ni) { accg[mi][ni] = zero; accu[mi][ni] = zero; }

  const int r0 = tid >> 2;
  const int c0 = (tid & 3) * 8;

  for (int kt = 0; kt < Kd; kt += 32) {
    __syncthreads();
    uint4 a0 = *(const uint4*)(A + (size_t)(m0 + r0) * Kd + kt + c0);
    uint4 a1 = *(const uint4*)(A + (size_t)(m0 + r0 + 64) * Kd + kt + c0);
    uint4 g0 = pack8(Wg + (size_t)(n0 + r0) * Kd + kt + c0);
    uint4 g1 = pack8(Wg + (size_t)(n0 + r0 + 64) * Kd + kt + c0);
    uint4 u0 = pack8(Wu + (size_t)(n0 + r0) * Kd + kt + c0);
    uint4 u1 = pack8(Wu + (size_t)(n0 + r0 + 64) * Kd + kt + c0);
    *(uint4*)&Asm[r0 * 40 + c0] = a0;
    *(uint4*)&Asm[(r0 + 64) * 40 + c0] = a1;
    *(uint4*)&Gsm[r0 * 40 + c0] = g0;
    *(uint4*)&Gsm[(r0 + 64) * 40 + c0] = g1;
    *(uint4*)&Usm[r0 * 40 + c0] = u0;
    *(uint4*)&Usm[(r0 + 64) * 40 + c0] = u1;
    __syncthreads();
    bf16x8 af[4];
#pragma unroll
    for (int mi = 0; mi < 4; ++mi)
      af[mi] = *(const bf16x8*)&Asm[(wr * 64 + mi * 16 + l15) * 40 + quad * 8];
#pragma unroll
    for (int ni = 0; ni < 4; ++ni) {
      bf16x8 bg = *(const bf16x8*)&Gsm[(wc * 64 + ni * 16 + l15) * 40 + quad * 8];
      bf16x8 bu = *(const bf16x8*)&Usm[(wc * 64 + ni * 16 + l15) * 40 + quad * 8];
#pragma unroll
      for (int mi = 0; mi < 4; ++mi) {
        accg[mi][ni] = mfma16(af[mi], bg, accg[mi][ni]);
        accu[mi][ni] = mfma16(af[mi], bu, accu[mi][ni]);
      }
    }
  }

#pragma unroll
  for (int mi = 0; mi < 4; ++mi) {
    const int mb = m0 + wr * 64 + mi * 16 + quad * 4;
#pragma unroll
    for (int ni = 0; ni < 4; ++ni) {
      const int n = n0 + wc * 64 + ni * 16 + l15;
#pragma unroll
      for (int r = 0; r < 4; ++r) {
        float g = accg[mi][ni][r];
        float u = accu[mi][ni][r];
        float act = g / (1.f + __expf(-g)) * u;
        C[(size_t)(mb + r) * N + n] = (bf16_t)act;
      }
    }
  }
}

__global__ __launch_bounds__(256) void attn_kernel(const bf16_t* __restrict__ qbuf,
                                                   const float* __restrict__ kbuf,
                                                   const float* __restrict__ vbuf,
                                                   const int* __restrict__ cuq,
                                                   const int* __restrict__ cuk,
                                                   bf16_t* __restrict__ obuf) {
  const int qt = blockIdx.x, h = blockIdx.y, b = blockIdx.z;
  const int hk = h >> 2;
  const int tid = threadIdx.x;
  const int wid = tid >> 6, lane = tid & 63, quad = lane >> 4, l15 = lane & 15;
  __shared__ __align__(16) bf16_t Kt[64 * 72];
  __shared__ __align__(16) bf16_t Vt[64 * 72];
  __shared__ __align__(16) bf16_t Pt[64 * 72];
  const int cq1 = cuq[1], ck1 = cuk[1];

  const int qrow_a = qt * 64 + wid * 16 + l15;
  const bf16_t* qp = qbuf + ((size_t)(b * SEQQ + qrow_a)) * HIDDEN + h * HD;
  bf16x8 qf0 = *(const bf16x8*)(qp + quad * 8);
  bf16x8 qf1 = *(const bf16x8*)(qp + 32 + quad * 8);

  floatx4 Of[4];
  floatx4 zero = {0.f, 0.f, 0.f, 0.f};
#pragma unroll
  for (int df = 0; df < 4; ++df) Of[df] = zero;
  float m_r[4], l_r[4];
#pragma unroll
  for (int r = 0; r < 4; ++r) { m_r[r] = -1e30f; l_r[r] = 0.f; }
  const int q_row0 = qt * 64 + wid * 16 + quad * 4;
  int seg_q[4];
#pragma unroll
  for (int r = 0; r < 4; ++r) seg_q[r] = (q_row0 + r >= cq1) ? 1 : 0;
  const bool blk_seg1 = (qt * 64 >= cq1);

  const int stag_row = tid >> 3;
  const int stag_c = (tid & 7) * 8;
  const int kt_start = blk_seg1 ? (ck1 >> 6) : 0;

  for (int kt = kt_start; kt <= qt; ++kt) {
    __syncthreads();
#pragma unroll
    for (int i = 0; i < 2; ++i) {
      const int row = stag_row + i * 32;
      const size_t goff = ((size_t)((b * SEQK + kt * 64 + row) * NKV + hk)) * HD + stag_c;
      uint4 kv = pack8(kbuf + goff);
      *(uint4*)&Kt[row * 72 + stag_c] = kv;
      union { uint4 u; bf16_t e[8]; } vv;
      vv.u = pack8(vbuf + goff);
#pragma unroll
      for (int j = 0; j < 8; ++j) Vt[(stag_c + j) * 72 + row] = vv.e[j];
    }
    __syncthreads();

    floatx4 sf[4];
#pragma unroll
    for (int nf = 0; nf < 4; ++nf) {
      bf16x8 kf0 = *(const bf16x8*)&Kt[(nf * 16 + l15) * 72 + quad * 8];
      bf16x8 kf1 = *(const bf16x8*)&Kt[(nf * 16 + l15) * 72 + 32 + quad * 8];
      floatx4 a = zero;
      a = mfma16(qf0, kf0, a);
      a = mfma16(qf1, kf1, a);
      sf[nf] = a;
    }

    float tmax[4];
#pragma unroll
    for (int r = 0; r < 4; ++r) tmax[r] = NEGBIG;
#pragma unroll
    for (int nf = 0; nf < 4; ++nf) {
      const int kg = kt * 64 + nf * 16 + l15;
#pragma unroll
      for (int r = 0; r < 4; ++r) {
        const int qg = q_row0 + r;
        const int sk = (kg >= ck1) ? 1 : 0;
        float s = sf[nf][r] * 0.125f;
        bool ok = (kg <= qg) && (sk == seg_q[r]);
        s = ok ? s : NEGBIG;
        sf[nf][r] = s;
        tmax[r] = fmaxf(tmax[r], s);
      }
    }
#pragma unroll
    for (int r = 0; r < 4; ++r) {
#pragma unroll
      for (int off = 1; off <= 8; off <<= 1) tmax[r] = fmaxf(tmax[r], __shfl_xor(tmax[r], off));
    }
    float alpha[4], rsum[4];
#pragma unroll
    for (int r = 0; r < 4; ++r) {
      float mn = fmaxf(m_r[r], tmax[r]);
      alpha[r] = __expf(m_r[r] - mn);
      m_r[r] = mn;
      rsum[r] = 0.f;
    }
#pragma unroll
    for (int nf = 0; nf < 4; ++nf) {
#pragma unroll
      for (int r = 0; r < 4; ++r) {
        float p = __expf(sf[nf][r] - m_r[r]);
        rsum[r] += p;
        Pt[(wid * 16 + quad * 4 + r) * 72 + nf * 16 + l15] = (bf16_t)p;
      }
    }
#pragma unroll
    for (int r = 0; r < 4; ++r) {
#pragma unroll
      for (int off = 1; off <= 8; off <<= 1) rsum[r] += __shfl_xor(rsum[r], off);
      l_r[r] = alpha[r] * l_r[r] + rsum[r];
    }
#pragma unroll
    for (int df = 0; df < 4; ++df) {
#pragma unroll
      for (int r = 0; r < 4; ++r) Of[df][r] *= alpha[r];
    }
#pragma unroll
    for (int kk = 0; kk < 2; ++kk) {
      bf16x8 pf = *(const bf16x8*)&Pt[(wid * 16 + l15) * 72 + kk * 32 + quad * 8];
#pragma unroll
      for (int df = 0; df < 4; ++df) {
        bf16x8 vf = *(const bf16x8*)&Vt[(df * 16 + l15) * 72 + kk * 32 + quad * 8];
        Of[df] = mfma16(pf, vf, Of[df]);
      }
    }
  }

  float inv[4];
#pragma unroll
  for (int r = 0; r < 4; ++r) inv[r] = (l_r[r] > 0.f) ? 1.f / l_r[r] : 0.f;
#pragma unroll
  for (int df = 0; df < 4; ++df) {
#pragma unroll
    for (int r = 0; r < 4; ++r) {
      obuf[((size_t)(b * SEQQ + q_row0 + r)) * HIDDEN + h * HD + df * 16 + l15] =
          (bf16_t)(Of[df][r] * inv[r]);
    }
  }
}

static inline int cvt_grid(int n8) {
  int g = (n8 + 255) / 256;
  return g > 2048 ? 2048 : g;
}

extern "C" void kernel_launch(void* const* d_in, const int* in_sizes, int n_in,
                              void* d_out, int out_size, void* d_ws, size_t ws_size,
                              hipStream_t stream) {
  const float* x    = (const float*)d_in[0];   // hidden_states [2,2048,2048] f32
  const float* kst  = (const float*)d_in[1];   // key_states   [2,2048,8,64] f32
  const float* vst  = (const float*)d_in[2];   // value_states [2,2048,8,64] f32
  const float* wln1 = (const float*)d_in[4];
  const float* wln2 = (const float*)d_in[5];
  const float* wq   = (const float*)d_in[6];   // [2048,2048] f32
  const float* wo   = (const float*)d_in[7];   // [2048,2048] f32
  const float* wg   = (const float*)d_in[8];   // [8192,2048] f32
  const float* wu   = (const float*)d_in[9];   // [8192,2048] f32
  const float* wd   = (const float*)d_in[10];  // [2048,8192] f32
  const int* cuq    = (const int*)d_in[11];
  const int* cuk    = (const int*)d_in[12];
  float* out = (float*)d_out;                  // f32; also holds `hidden`

  const size_t MB = 1024ull * 1024ull;
  char* ws = (char*)d_ws;
  const bool full = ws_size >= 200 * MB;
  const bool conv = ws_size >= 168 * MB;

  if (conv) {
    bf16_t* bufA = (bf16_t*)ws;                         // 16 MiB
    bf16_t* bufB = (bf16_t*)(ws + 16 * MB);             // 64 (full) / 32 MiB
    char* p = ws + 16 * MB + (full ? 64 : 32) * MB;
    bf16_t* wq16 = (bf16_t*)p; p += 8 * MB;
    bf16_t* wo16 = (bf16_t*)p; p += 8 * MB;
    bf16_t* wg16 = (bf16_t*)p; p += 32 * MB;
    bf16_t* wu16 = (bf16_t*)p; p += 32 * MB;
    bf16_t* wd16 = (bf16_t*)p; p += 32 * MB;
    bf16_t* k16  = (bf16_t*)p; p += 4 * MB;
    bf16_t* v16  = (bf16_t*)p;

    const int n8_qo = 2048 * 2048 / 8;
    const int n8_gud = 8192 * 2048 / 8;
    const int n8_kv = NBATCH * SEQK * NKV * HD / 8;
    cvt_kernel<<<cvt_grid(n8_qo), 256, 0, stream>>>(wq, wq16, n8_qo);
    cvt_kernel<<<cvt_grid(n8_qo), 256, 0, stream>>>(wo, wo16, n8_qo);
    cvt_kernel<<<cvt_grid(n8_gud), 256, 0, stream>>>(wg, wg16, n8_gud);
    cvt_kernel<<<cvt_grid(n8_gud), 256, 0, stream>>>(wu, wu16, n8_gud);
    cvt_kernel<<<cvt_grid(n8_gud), 256, 0, stream>>>(wd, wd16, n8_gud);
    cvt_kernel<<<cvt_grid(n8_kv), 256, 0, stream>>>(kst, k16, n8_kv);
    cvt_kernel<<<cvt_grid(n8_kv), 256, 0, stream>>>(vst, v16, n8_kv);

    // 1. normed = rmsnorm(x, ln1) -> bf16
    rmsnorm_kernel<<<4096, 256, 0, stream>>>(x, wln1, bufA);
    // 2. q = normed @ wq^T -> bf16
    gemm_bt16<0, bf16_t><<<dim3(16, 32), 256, 0, stream>>>(bufA, wq16, nullptr, bufB, 2048, 2048);
    // 3. attn (GQA-shared staging) -> bf16
    attn_gqa<<<dim3(32, 16, 2), 256, 0, stream>>>(bufB, k16, v16, cuq, cuk, bufA);
    // 4. hidden = x + attn @ wo^T (f32, in d_out)
    gemm_bt16<1, float><<<dim3(16, 32), 256, 0, stream>>>(bufA, wo16, x, out, 2048, 2048);
    // 5. normed2 = rmsnorm(hidden, ln2) -> bf16
    rmsnorm_kernel<<<4096, 256, 0, stream>>>(out, wln2, bufA);
    // 6/7. MLP
    const int nch = full ? 1 : 2;
    const int mch = 4096 / nch;
    for (int c = 0; c < nch; ++c) {
      const size_t off = (size_t)c * mch;
      gateup16<<<dim3(128, mch / 128), 256, 0, stream>>>(bufA + off * HIDDEN, wg16, wu16,
                                                         bufB, 2048, 8192);
      gemm_bt16<1, float><<<dim3(16, mch / 128), 256, 0, stream>>>(bufB, wd16, out + off * HIDDEN,
                                                                   out + off * HIDDEN, 8192, 2048);
    }
  } else {
    // Legacy path (48 MiB workspace): on-the-fly f32->bf16 in each GEMM.
    bf16_t* bufA = (bf16_t*)ws;
    bf16_t* bufB = (bf16_t*)(ws + 16 * MB);
    rmsnorm_kernel<<<4096, 256, 0, stream>>>(x, wln1, bufA);
    gemm_bt<0, bf16_t><<<dim3(16, 32), 256, 0, stream>>>(bufA, wq, nullptr, bufB, 2048, 2048);
    attn_kernel<<<dim3(32, 32, 2), 256, 0, stream>>>(bufB, kst, vst, cuq, cuk, bufA);
    gemm_bt<1, float><<<dim3(16, 32), 256, 0, stream>>>(bufA, wo, x, out, 2048, 2048);
    rmsnorm_kernel<<<4096, 256, 0, stream>>>(out, wln2, bufA);
    for (int c = 0; c < 2; ++c) {
      const size_t off = (size_t)c * 2048;
      gemm_gateup<<<dim3(64, 16), 256, 0, stream>>>(bufA + off * HIDDEN, wg, wu, bufB, 2048, 8192);
      gemm_bt<1, float><<<dim3(16, 16), 256, 0, stream>>>(bufB, wd, out + off * HIDDEN,
                                                          out + off * HIDDEN, 8192, 2048);
    }
  }
}